// Round 1
// baseline (129.814 us; speedup 1.0000x reference)
//
#include <hip/hip_runtime.h>
#include <math.h>

namespace {
constexpr int kN = 22;
constexpr int kF = 448;
constexpr int kNP = kN * kN;          // 484
// kernel1 shared pool (floats): corr role needs 22*452 + 44 = 9988 (39.95 KB)
constexpr int kXStr = 452;            // 452%4==0 (16B rows), 452%32==4 (bank spread)
constexpr int kSm1 = kN * kXStr + 2 * kN;   // 9988
// GEMM role overlays: As [64][36] = 2304, Bs [64][68] = 4352  (6656 total)
constexpr int kAStr = 36;
constexpr int kBStr = 68;
// kernel2
constexpr int kPStr = 68;
}

// =================== kernel 1: projections GEMM + corr ======================
// blocks [0, nGemm): 32x64 SGEMM tiles of C = A(M,448) @ W(448,256)
//   col tiles: 0:a1(cw1[0:448],+cb1) 1:a2(cw1[448:896]) 2:u1(sw1[128:576],+emb@sw1[0:64],+sb1)
//              3:u2(sw1[576:1024],+emb@sw1[64:128])
// blocks [nGemm, nGemm+B): per-b corr stats + |corr| unique pairs (i<=j), mirrored write
__global__ __launch_bounds__(256) void hgc_k1(
    const float* __restrict__ x,
    const float* __restrict__ cw1, const float* __restrict__ cb1,
    const float* __restrict__ emb,
    const float* __restrict__ sw1, const float* __restrict__ sb1,
    float* __restrict__ C, float* __restrict__ g,
    int M, int Mtiles, int nGemm)
{
    __shared__ __align__(16) float sm[kSm1];
    const int tid = threadIdx.x;

    if ((int)blockIdx.x < nGemm) {
        // ---------------- GEMM role ----------------
        float* As = sm;                 // [64][kAStr] transposed: As[k][m]
        float* Bs = sm + 64 * kAStr;    // [64][kBStr]: Bs[k][n]
        const int bm = blockIdx.x % Mtiles;
        const int bn = blockIdx.x / Mtiles;        // 0..3
        const int m0 = bm * 32;

        const float* Wsrc =
            (bn == 0) ? cw1 :
            (bn == 1) ? cw1 + 448 * 64 :
            (bn == 2) ? sw1 + 128 * 64 :
                        sw1 + 576 * 64;

        const int tm = tid & 15;        // m-group: rows tm*2, tm*2+1
        const int tn = tid >> 4;        // n-group: cols tn*4 .. +3
        float acc[2][4];
        #pragma unroll
        for (int i = 0; i < 2; ++i)
            #pragma unroll
            for (int j = 0; j < 4; ++j) acc[i][j] = 0.f;

        for (int k0 = 0; k0 < kF; k0 += 64) {
            // stage A (32 rows x 64 k), transposed
            #pragma unroll
            for (int pass = 0; pass < 2; ++pass) {
                const int idx = tid + pass * 256;       // 512 float4
                const int row = idx >> 4, kq = idx & 15;
                const int m = m0 + row;
                float4 v = {0, 0, 0, 0};
                if (m < M) v = *(const float4*)&x[(size_t)m * kF + k0 + kq * 4];
                As[(kq * 4 + 0) * kAStr + row] = v.x;
                As[(kq * 4 + 1) * kAStr + row] = v.y;
                As[(kq * 4 + 2) * kAStr + row] = v.z;
                As[(kq * 4 + 3) * kAStr + row] = v.w;
            }
            // stage B (64 k x 64 n)
            #pragma unroll
            for (int pass = 0; pass < 4; ++pass) {
                const int idx = tid + pass * 256;       // 1024 float4
                const int k = idx >> 4, nq = idx & 15;
                const float4 v = *(const float4*)&Wsrc[(size_t)(k0 + k) * 64 + nq * 4];
                *(float4*)&Bs[k * kBStr + nq * 4] = v;
            }
            __syncthreads();
            #pragma unroll 8
            for (int k = 0; k < 64; ++k) {
                const float2 a2 = *(const float2*)&As[k * kAStr + tm * 2];
                const float4 b4 = *(const float4*)&Bs[k * kBStr + tn * 4];
                acc[0][0] = fmaf(a2.x, b4.x, acc[0][0]);
                acc[0][1] = fmaf(a2.x, b4.y, acc[0][1]);
                acc[0][2] = fmaf(a2.x, b4.z, acc[0][2]);
                acc[0][3] = fmaf(a2.x, b4.w, acc[0][3]);
                acc[1][0] = fmaf(a2.y, b4.x, acc[1][0]);
                acc[1][1] = fmaf(a2.y, b4.y, acc[1][1]);
                acc[1][2] = fmaf(a2.y, b4.z, acc[1][2]);
                acc[1][3] = fmaf(a2.y, b4.w, acc[1][3]);
            }
            __syncthreads();
        }

        // emb epilogue for u1/u2 tiles: extra K=64 with A=emb[r(m)], B=sw1[0:64 or 64:128]
        if (bn >= 2) {
            const float* W2 = sw1 + (bn == 2 ? 0 : 64) * 64;
            #pragma unroll
            for (int pass = 0; pass < 2; ++pass) {
                const int idx = tid + pass * 256;
                const int row = idx >> 4, kq = idx & 15;
                const int r = (m0 + row) % kN;
                const float4 v = *(const float4*)&emb[(size_t)r * 64 + kq * 4];
                As[(kq * 4 + 0) * kAStr + row] = v.x;
                As[(kq * 4 + 1) * kAStr + row] = v.y;
                As[(kq * 4 + 2) * kAStr + row] = v.z;
                As[(kq * 4 + 3) * kAStr + row] = v.w;
            }
            #pragma unroll
            for (int pass = 0; pass < 4; ++pass) {
                const int idx = tid + pass * 256;
                const int k = idx >> 4, nq = idx & 15;
                const float4 v = *(const float4*)&W2[(size_t)k * 64 + nq * 4];
                *(float4*)&Bs[k * kBStr + nq * 4] = v;
            }
            __syncthreads();
            #pragma unroll 8
            for (int k = 0; k < 64; ++k) {
                const float2 a2 = *(const float2*)&As[k * kAStr + tm * 2];
                const float4 b4 = *(const float4*)&Bs[k * kBStr + tn * 4];
                acc[0][0] = fmaf(a2.x, b4.x, acc[0][0]);
                acc[0][1] = fmaf(a2.x, b4.y, acc[0][1]);
                acc[0][2] = fmaf(a2.x, b4.z, acc[0][2]);
                acc[0][3] = fmaf(a2.x, b4.w, acc[0][3]);
                acc[1][0] = fmaf(a2.y, b4.x, acc[1][0]);
                acc[1][1] = fmaf(a2.y, b4.y, acc[1][1]);
                acc[1][2] = fmaf(a2.y, b4.z, acc[1][2]);
                acc[1][3] = fmaf(a2.y, b4.w, acc[1][3]);
            }
        }

        float4 bias = {0, 0, 0, 0};
        if (bn == 0)      bias = *(const float4*)&cb1[tn * 4];
        else if (bn == 2) bias = *(const float4*)&sb1[tn * 4];
        #pragma unroll
        for (int i = 0; i < 2; ++i) {
            const int m = m0 + tm * 2 + i;
            if (m < M) {
                float4 o;
                o.x = acc[i][0] + bias.x; o.y = acc[i][1] + bias.y;
                o.z = acc[i][2] + bias.z; o.w = acc[i][3] + bias.w;
                *(float4*)&C[(size_t)m * 256 + bn * 64 + tn * 4] = o;
            }
        }
    } else {
        // ---------------- corr role: one block per b, unique pairs only ----------------
        float* smu = sm + kN * kXStr;
        float* sis = smu + kN;
        const int b = blockIdx.x - nGemm;

        const float4* xb4 = (const float4*)(x + (size_t)b * (kN * kF));
        for (int idx = tid; idx < kN * kF / 4; idx += 256) {
            const float4 v = xb4[idx];
            const int r = idx / 112;
            const int k = (idx - r * 112) * 4;
            float* d = sm + r * kXStr + k;
            d[0] = v.x; d[1] = v.y; d[2] = v.z; d[3] = v.w;
        }
        __syncthreads();

        {
            const int wid = tid >> 6, lane = tid & 63;
            for (int r = wid; r < kN; r += 4) {
                const float* row = sm + r * kXStr;
                float s = 0.f;
                #pragma unroll
                for (int c = 0; c < 7; ++c) s += row[c * 64 + lane];
                #pragma unroll
                for (int o = 32; o; o >>= 1) s += __shfl_xor(s, o, 64);
                const float mean = s * (1.f / 448.f);
                float ss = 0.f;
                #pragma unroll
                for (int c = 0; c < 7; ++c) { const float d = row[c * 64 + lane] - mean; ss = fmaf(d, d, ss); }
                #pragma unroll
                for (int o = 32; o; o >>= 1) ss += __shfl_xor(ss, o, 64);
                if (lane == 0) {
                    smu[r] = mean;
                    sis[r] = 1.f / (sqrtf(ss * (1.f / 447.f)) + 1e-8f);   // ddof=1
                }
            }
        }
        __syncthreads();

        // 253 unique pairs (i<=j); |corr| is symmetric, mirror the write.
        if (tid < 253) {
            int i = 0, rem = tid;
            while (rem >= kN - i) { rem -= kN - i; ++i; }
            const int j = i + rem;
            const float4* ri = (const float4*)(sm + i * kXStr);
            const float4* rj = (const float4*)(sm + j * kXStr);
            // 4 independent accumulators: break the 448-deep FMA dependency chain
            float d0 = 0.f, d1 = 0.f, d2 = 0.f, d3 = 0.f;
            for (int q = 0; q < 112; ++q) {
                const float4 a = ri[q], bq = rj[q];
                d0 = fmaf(a.x, bq.x, d0); d1 = fmaf(a.y, bq.y, d1);
                d2 = fmaf(a.z, bq.z, d2); d3 = fmaf(a.w, bq.w, d3);
            }
            const float dot = (d0 + d1) + (d2 + d3);
            const float c = (dot - 448.f * smu[i] * smu[j]) * sis[i] * sis[j] * (1.f / 448.f);
            const float av = fabsf(c);
            g[(size_t)b * kNP + i * 22 + j] = av;
            if (i != j) g[(size_t)b * kNP + j * 22 + i] = av;
        }
    }
}

// =================== kernel 2: 2 blocks/b, 242 pairs each ===================
__global__ __launch_bounds__(256) void hgc_k2(
    const float* __restrict__ C, const float* __restrict__ g,
    const float* __restrict__ cw2, const float* __restrict__ cb2,
    const float* __restrict__ sw2, const float* __restrict__ sb2,
    const float* __restrict__ sw3, const float* __restrict__ sb3,
    const float* __restrict__ ln_g, const float* __restrict__ ln_b,
    const float* __restrict__ thr, const float* __restrict__ alpha_p,
    float* __restrict__ out)
{
    __shared__ __align__(16) float sp[4 * kN * kPStr];   // a1|a2|u1|u2, padded rows
    __shared__ float sg[kNP];
    __shared__ __align__(16) float sw2s[2048];
    __shared__ float scw2[64], slng[64], slnb[64], ssw3[32], ssb2[32];
    __shared__ float vbuf[32 * 66];

    const int tid = threadIdx.x;
    const int b   = blockIdx.x >> 1;
    const int pb  = blockIdx.x & 1;

    // hoist tiny scalar params once per thread
    const float cb2v  = cb2[0];
    const float sb3v  = sb3[0];
    const float tt    = 1.f / (1.f + expf(-thr[0]));      // accurate: feeds hard compare
    const float alpha = 1.f / (1.f + __expf(-alpha_p[0]));

    // stage the four 22x64 projection arrays from C rows (b*22+r), col block a*64
    #pragma unroll
    for (int a = 0; a < 4; ++a) {
        float* dst = sp + a * kN * kPStr;
        for (int idx = tid; idx < 352; idx += 256) {
            const int r = idx >> 4, kq = idx & 15;
            const float4 v = *(const float4*)&C[((size_t)(b * 22 + r)) * 256 + a * 64 + kq * 4];
            *(float4*)&dst[r * kPStr + kq * 4] = v;
        }
    }
    for (int idx = tid; idx < kNP; idx += 256) sg[idx] = g[(size_t)b * kNP + idx];
    {
        const float4* s4 = (const float4*)sw2;
        for (int idx = tid; idx < 512; idx += 256)
            *((float4*)(sw2s + idx * 4)) = s4[idx];
    }
    if (tid < 64)       { scw2[tid] = cw2[tid]; slng[tid] = ln_g[tid]; slnb[tid] = ln_b[tid]; }
    else if (tid < 96)  { ssw3[tid - 64] = sw3[tid - 64]; }
    else if (tid < 128) { ssb2[tid - 96] = sb2[tid - 96]; }
    __syncthreads();

    const int pl = tid >> 3;             // local pair slot 0..31
    const int t  = tid & 7;              // lane within pair group
    const float* sa1 = sp;
    const float* sa2 = sp + kN * kPStr;
    const float* su1 = sp + 2 * kN * kPStr;
    const float* su2 = sp + 3 * kN * kPStr;

    for (int ch = 0; ch < 8; ++ch) {
        const int lp = ch * 32 + pl;                 // 0..255
        const bool valid = lp < 242;
        const int p = valid ? (pb * 242 + lp) : 0;   // 484 = 2*242 exactly
        const int i = p / 22, j = p - (p / 22) * 22;

        // correlation edge weight: sigmoid(relu(a1_i + a2_j) . cw2 + cb2)
        float zc = 0.f;
        {
            const float* pa1 = sa1 + i * kPStr + t * 8;
            const float* pa2 = sa2 + j * kPStr + t * 8;
            #pragma unroll
            for (int c = 0; c < 8; ++c) {
                const float h = fmaxf(pa1[c] + pa2[c], 0.f);
                zc = fmaf(h, scw2[t * 8 + c], zc);
            }
            zc += __shfl_xor(zc, 1, 64); zc += __shfl_xor(zc, 2, 64); zc += __shfl_xor(zc, 4, 64);
        }
        const float wc = 1.f / (1.f + __expf(-(zc + cb2v)));

        // semantic branch
        const int lo = (i < j) ? i : j, hi = (i < j) ? j : i;
        const float* pu1 = su1 + lo * kPStr + t * 8;
        const float* pu2 = su2 + hi * kPStr + t * 8;
        float raw[8];
        float s1 = 0.f;
        #pragma unroll
        for (int c = 0; c < 8; ++c) { raw[c] = pu1[c] + pu2[c]; s1 += raw[c]; }
        s1 += __shfl_xor(s1, 1, 64); s1 += __shfl_xor(s1, 2, 64); s1 += __shfl_xor(s1, 4, 64);
        const float mean = s1 * (1.f / 64.f);
        float s2 = 0.f;
        #pragma unroll
        for (int c = 0; c < 8; ++c) { const float d = raw[c] - mean; s2 = fmaf(d, d, s2); }
        s2 += __shfl_xor(s2, 1, 64); s2 += __shfl_xor(s2, 2, 64); s2 += __shfl_xor(s2, 4, 64);
        const float rstd = rsqrtf(s2 * (1.f / 64.f) + 1e-5f);
        {
            float* vb = vbuf + pl * 66 + t * 8;
            #pragma unroll
            for (int c = 0; c < 8; ++c) {
                const int k = t * 8 + c;
                float v = (raw[c] - mean) * rstd;
                v = fmaf(v, slng[k], slnb[k]);
                vb[c] = fmaxf(v, 0.f);
            }
        }
        // vbuf slot pl is produced and consumed by the same 8 lanes of one wave:
        // same-wave LDS ops complete in order; a full block barrier is unnecessary.
        asm volatile("s_waitcnt lgkmcnt(0)" ::: "memory");

        // 64x32 GEMV: lane owns outputs o = t*4 .. t*4+3
        float4 acc = {0, 0, 0, 0};
        {
            const float* vb = vbuf + pl * 66;
            for (int k = 0; k < 64; ++k) {
                const float v = vb[k];
                const float4 w = *((const float4*)(sw2s + k * 32 + t * 4));
                acc.x = fmaf(v, w.x, acc.x); acc.y = fmaf(v, w.y, acc.y);
                acc.z = fmaf(v, w.z, acc.z); acc.w = fmaf(v, w.w, acc.w);
            }
        }
        float z2;
        {
            const int o0 = t * 4;
            z2  = fmaxf(acc.x + ssb2[o0 + 0], 0.f) * ssw3[o0 + 0];
            z2 += fmaxf(acc.y + ssb2[o0 + 1], 0.f) * ssw3[o0 + 1];
            z2 += fmaxf(acc.z + ssb2[o0 + 2], 0.f) * ssw3[o0 + 2];
            z2 += fmaxf(acc.w + ssb2[o0 + 3], 0.f) * ssw3[o0 + 3];
            z2 += __shfl_xor(z2, 1, 64); z2 += __shfl_xor(z2, 2, 64); z2 += __shfl_xor(z2, 4, 64);
        }

        if (valid && t == 0) {
            float gsem;
            if (i == j) {
                gsem = 1.f;
            } else {
                // accurate expf: this sigmoid feeds a hard threshold compare
                const float wsem = 1.f / (1.f + expf(-(z2 + sb3v)));
                gsem = (wsem > tt) ? wsem : 0.f;
            }
            const float gcorr = fmaf(sg[p], wc, (i == j) ? 1.f : 0.f);
            out[(size_t)b * kNP + p] = fmaf(alpha, gcorr, (1.f - alpha) * gsem);
        }
    }
}

extern "C" void kernel_launch(void* const* d_in, const int* in_sizes, int n_in,
                              void* d_out, int out_size, void* d_ws, size_t ws_size,
                              hipStream_t stream)
{
    (void)n_in; (void)out_size; (void)ws_size;
    const float* x     = (const float*)d_in[0];
    const float* cw1   = (const float*)d_in[1];
    const float* cb1   = (const float*)d_in[2];
    const float* cw2   = (const float*)d_in[3];
    const float* cb2   = (const float*)d_in[4];
    const float* emb   = (const float*)d_in[5];
    const float* sw1   = (const float*)d_in[6];
    const float* sb1   = (const float*)d_in[7];
    const float* ln_g  = (const float*)d_in[8];
    const float* ln_b  = (const float*)d_in[9];
    const float* sw2   = (const float*)d_in[10];
    const float* sb2   = (const float*)d_in[11];
    const float* sw3   = (const float*)d_in[12];
    const float* sb3   = (const float*)d_in[13];
    const float* thr   = (const float*)d_in[14];
    const float* alpha = (const float*)d_in[15];
    float* out = (float*)d_out;
    float* ws  = (float*)d_ws;

    const int B = in_sizes[0] / (kN * kF);
    const int M = kN * B;
    const int Mtiles = (M + 31) / 32;
    const int nGemm = Mtiles * 4;

    float* C = ws;                           // M x 256
    float* g = ws + (size_t)M * 256;         // B x 484

    hipLaunchKernelGGL(hgc_k1, dim3(nGemm + B), dim3(256), 0, stream,
                       x, cw1, cb1, emb, sw1, sb1, C, g, M, Mtiles, nGemm);
    hipLaunchKernelGGL(hgc_k2, dim3(2 * B), dim3(256), 0, stream,
                       C, g, cw2, cb2, sw2, sb2, sw3, sb3, ln_g, ln_b, thr, alpha, out);
}

// Round 2
// 123.523 us; speedup vs baseline: 1.0509x; 1.0509x over previous
//
#include <hip/hip_runtime.h>
#include <math.h>

namespace {
constexpr int kN = 22;
constexpr int kF = 448;
constexpr int kNP = kN * kN;          // 484
// kernel1 shared pool (floats): corr role needs 22*452 + 44 = 9988 (39.95 KB)
constexpr int kXStr = 452;            // 452%4==0 (16B rows), 452%32==4 (bank spread)
constexpr int kSm1 = kN * kXStr + 2 * kN;   // 9988
// GEMM role overlays: As [64][36] = 2304, Bs [64][68] = 4352  (6656 total)
constexpr int kAStr = 36;
constexpr int kBStr = 68;
// kernel2
constexpr int kPStr = 68;
}

// =================== kernel 1: projections GEMM + corr ======================
// blocks [0, nGemm): 32x64 SGEMM tiles of C = A(M,448) @ W(448,256)
//   col tiles: 0:a1(cw1[0:448],+cb1) 1:a2(cw1[448:896]) 2:u1(sw1[128:576],+emb@sw1[0:64],+sb1)
//              3:u2(sw1[576:1024],+emb@sw1[64:128])
// blocks [nGemm, nGemm+B): per-b corr stats + |corr| unique pairs (i<=j), mirrored write
__global__ __launch_bounds__(256) void hgc_k1(
    const float* __restrict__ x,
    const float* __restrict__ cw1, const float* __restrict__ cb1,
    const float* __restrict__ emb,
    const float* __restrict__ sw1, const float* __restrict__ sb1,
    float* __restrict__ C, float* __restrict__ g,
    int M, int Mtiles, int nGemm)
{
    __shared__ __align__(16) float sm[kSm1];
    const int tid = threadIdx.x;

    if ((int)blockIdx.x < nGemm) {
        // ---------------- GEMM role ----------------
        float* As = sm;                 // [64][kAStr] transposed: As[k][m]
        float* Bs = sm + 64 * kAStr;    // [64][kBStr]: Bs[k][n]
        const int bm = blockIdx.x % Mtiles;
        const int bn = blockIdx.x / Mtiles;        // 0..3
        const int m0 = bm * 32;

        const float* Wsrc =
            (bn == 0) ? cw1 :
            (bn == 1) ? cw1 + 448 * 64 :
            (bn == 2) ? sw1 + 128 * 64 :
                        sw1 + 576 * 64;

        const int tm = tid & 15;        // m-group: rows tm*2, tm*2+1
        const int tn = tid >> 4;        // n-group: cols tn*4 .. +3
        float acc[2][4];
        #pragma unroll
        for (int i = 0; i < 2; ++i)
            #pragma unroll
            for (int j = 0; j < 4; ++j) acc[i][j] = 0.f;

        for (int k0 = 0; k0 < kF; k0 += 64) {
            // stage A (32 rows x 64 k), transposed
            #pragma unroll
            for (int pass = 0; pass < 2; ++pass) {
                const int idx = tid + pass * 256;       // 512 float4
                const int row = idx >> 4, kq = idx & 15;
                const int m = m0 + row;
                float4 v = {0, 0, 0, 0};
                if (m < M) v = *(const float4*)&x[(size_t)m * kF + k0 + kq * 4];
                As[(kq * 4 + 0) * kAStr + row] = v.x;
                As[(kq * 4 + 1) * kAStr + row] = v.y;
                As[(kq * 4 + 2) * kAStr + row] = v.z;
                As[(kq * 4 + 3) * kAStr + row] = v.w;
            }
            // stage B (64 k x 64 n)
            #pragma unroll
            for (int pass = 0; pass < 4; ++pass) {
                const int idx = tid + pass * 256;       // 1024 float4
                const int k = idx >> 4, nq = idx & 15;
                const float4 v = *(const float4*)&Wsrc[(size_t)(k0 + k) * 64 + nq * 4];
                *(float4*)&Bs[k * kBStr + nq * 4] = v;
            }
            __syncthreads();
            #pragma unroll 8
            for (int k = 0; k < 64; ++k) {
                const float2 a2 = *(const float2*)&As[k * kAStr + tm * 2];
                const float4 b4 = *(const float4*)&Bs[k * kBStr + tn * 4];
                acc[0][0] = fmaf(a2.x, b4.x, acc[0][0]);
                acc[0][1] = fmaf(a2.x, b4.y, acc[0][1]);
                acc[0][2] = fmaf(a2.x, b4.z, acc[0][2]);
                acc[0][3] = fmaf(a2.x, b4.w, acc[0][3]);
                acc[1][0] = fmaf(a2.y, b4.x, acc[1][0]);
                acc[1][1] = fmaf(a2.y, b4.y, acc[1][1]);
                acc[1][2] = fmaf(a2.y, b4.z, acc[1][2]);
                acc[1][3] = fmaf(a2.y, b4.w, acc[1][3]);
            }
            __syncthreads();
        }

        // emb epilogue for u1/u2 tiles: extra K=64 with A=emb[r(m)], B=sw1[0:64 or 64:128]
        if (bn >= 2) {
            const float* W2 = sw1 + (bn == 2 ? 0 : 64) * 64;
            #pragma unroll
            for (int pass = 0; pass < 2; ++pass) {
                const int idx = tid + pass * 256;
                const int row = idx >> 4, kq = idx & 15;
                const int r = (m0 + row) % kN;
                const float4 v = *(const float4*)&emb[(size_t)r * 64 + kq * 4];
                As[(kq * 4 + 0) * kAStr + row] = v.x;
                As[(kq * 4 + 1) * kAStr + row] = v.y;
                As[(kq * 4 + 2) * kAStr + row] = v.z;
                As[(kq * 4 + 3) * kAStr + row] = v.w;
            }
            #pragma unroll
            for (int pass = 0; pass < 4; ++pass) {
                const int idx = tid + pass * 256;
                const int k = idx >> 4, nq = idx & 15;
                const float4 v = *(const float4*)&W2[(size_t)k * 64 + nq * 4];
                *(float4*)&Bs[k * kBStr + nq * 4] = v;
            }
            __syncthreads();
            #pragma unroll 8
            for (int k = 0; k < 64; ++k) {
                const float2 a2 = *(const float2*)&As[k * kAStr + tm * 2];
                const float4 b4 = *(const float4*)&Bs[k * kBStr + tn * 4];
                acc[0][0] = fmaf(a2.x, b4.x, acc[0][0]);
                acc[0][1] = fmaf(a2.x, b4.y, acc[0][1]);
                acc[0][2] = fmaf(a2.x, b4.z, acc[0][2]);
                acc[0][3] = fmaf(a2.x, b4.w, acc[0][3]);
                acc[1][0] = fmaf(a2.y, b4.x, acc[1][0]);
                acc[1][1] = fmaf(a2.y, b4.y, acc[1][1]);
                acc[1][2] = fmaf(a2.y, b4.z, acc[1][2]);
                acc[1][3] = fmaf(a2.y, b4.w, acc[1][3]);
            }
        }

        float4 bias = {0, 0, 0, 0};
        if (bn == 0)      bias = *(const float4*)&cb1[tn * 4];
        else if (bn == 2) bias = *(const float4*)&sb1[tn * 4];
        #pragma unroll
        for (int i = 0; i < 2; ++i) {
            const int m = m0 + tm * 2 + i;
            if (m < M) {
                float4 o;
                o.x = acc[i][0] + bias.x; o.y = acc[i][1] + bias.y;
                o.z = acc[i][2] + bias.z; o.w = acc[i][3] + bias.w;
                *(float4*)&C[(size_t)m * 256 + bn * 64 + tn * 4] = o;
            }
        }
    } else {
        // ---------------- corr role: one block per b, unique pairs only ----------------
        float* smu = sm + kN * kXStr;
        float* sis = smu + kN;
        const int b = blockIdx.x - nGemm;

        const float4* xb4 = (const float4*)(x + (size_t)b * (kN * kF));
        for (int idx = tid; idx < kN * kF / 4; idx += 256) {
            const float4 v = xb4[idx];
            const int r = idx / 112;
            const int k = (idx - r * 112) * 4;
            float* d = sm + r * kXStr + k;
            d[0] = v.x; d[1] = v.y; d[2] = v.z; d[3] = v.w;
        }
        __syncthreads();

        {
            const int wid = tid >> 6, lane = tid & 63;
            for (int r = wid; r < kN; r += 4) {
                const float* row = sm + r * kXStr;
                float s = 0.f;
                #pragma unroll
                for (int c = 0; c < 7; ++c) s += row[c * 64 + lane];
                #pragma unroll
                for (int o = 32; o; o >>= 1) s += __shfl_xor(s, o, 64);
                const float mean = s * (1.f / 448.f);
                float ss = 0.f;
                #pragma unroll
                for (int c = 0; c < 7; ++c) { const float d = row[c * 64 + lane] - mean; ss = fmaf(d, d, ss); }
                #pragma unroll
                for (int o = 32; o; o >>= 1) ss += __shfl_xor(ss, o, 64);
                if (lane == 0) {
                    smu[r] = mean;
                    sis[r] = 1.f / (sqrtf(ss * (1.f / 447.f)) + 1e-8f);   // ddof=1
                }
            }
        }
        __syncthreads();

        // 253 unique pairs (i<=j); |corr| is symmetric, mirror the write.
        if (tid < 253) {
            int i = 0, rem = tid;
            while (rem >= kN - i) { rem -= kN - i; ++i; }
            const int j = i + rem;
            const float4* ri = (const float4*)(sm + i * kXStr);
            const float4* rj = (const float4*)(sm + j * kXStr);
            // 4 independent accumulators: break the 448-deep FMA dependency chain
            float d0 = 0.f, d1 = 0.f, d2 = 0.f, d3 = 0.f;
            for (int q = 0; q < 112; ++q) {
                const float4 a = ri[q], bq = rj[q];
                d0 = fmaf(a.x, bq.x, d0); d1 = fmaf(a.y, bq.y, d1);
                d2 = fmaf(a.z, bq.z, d2); d3 = fmaf(a.w, bq.w, d3);
            }
            const float dot = (d0 + d1) + (d2 + d3);
            const float c = (dot - 448.f * smu[i] * smu[j]) * sis[i] * sis[j] * (1.f / 448.f);
            const float av = fabsf(c);
            g[(size_t)b * kNP + i * 22 + j] = av;
            if (i != j) g[(size_t)b * kNP + j * 22 + i] = av;
        }
    }
}

// =================== kernel 2: 4 blocks/b, 121 pairs each ===================
// 512 blocks = 2 blocks/CU = 2 waves/SIMD: the second wave hides shfl/LDS latency.
// (2 blocks/b = 1 wave/SIMD regressed +4.6us in round 1 — latency fully exposed.)
__global__ __launch_bounds__(256) void hgc_k2(
    const float* __restrict__ C, const float* __restrict__ g,
    const float* __restrict__ cw2, const float* __restrict__ cb2,
    const float* __restrict__ sw2, const float* __restrict__ sb2,
    const float* __restrict__ sw3, const float* __restrict__ sb3,
    const float* __restrict__ ln_g, const float* __restrict__ ln_b,
    const float* __restrict__ thr, const float* __restrict__ alpha_p,
    float* __restrict__ out)
{
    __shared__ __align__(16) float sp[4 * kN * kPStr];   // a1|a2|u1|u2, padded rows
    __shared__ float sg[kNP];
    __shared__ __align__(16) float sw2s[2048];
    __shared__ float scw2[64], slng[64], slnb[64], ssw3[32], ssb2[32];
    __shared__ float vbuf[32 * 66];

    const int tid = threadIdx.x;
    const int b   = blockIdx.x >> 2;
    const int pb  = blockIdx.x & 3;

    // hoist tiny scalar params once per thread
    const float cb2v  = cb2[0];
    const float sb3v  = sb3[0];
    const float tt    = 1.f / (1.f + expf(-thr[0]));      // accurate: feeds hard compare
    const float alpha = 1.f / (1.f + __expf(-alpha_p[0]));

    // stage the four 22x64 projection arrays from C rows (b*22+r), col block a*64
    #pragma unroll
    for (int a = 0; a < 4; ++a) {
        float* dst = sp + a * kN * kPStr;
        for (int idx = tid; idx < 352; idx += 256) {
            const int r = idx >> 4, kq = idx & 15;
            const float4 v = *(const float4*)&C[((size_t)(b * 22 + r)) * 256 + a * 64 + kq * 4];
            *(float4*)&dst[r * kPStr + kq * 4] = v;
        }
    }
    for (int idx = tid; idx < kNP; idx += 256) sg[idx] = g[(size_t)b * kNP + idx];
    {
        const float4* s4 = (const float4*)sw2;
        for (int idx = tid; idx < 512; idx += 256)
            *((float4*)(sw2s + idx * 4)) = s4[idx];
    }
    if (tid < 64)       { scw2[tid] = cw2[tid]; slng[tid] = ln_g[tid]; slnb[tid] = ln_b[tid]; }
    else if (tid < 96)  { ssw3[tid - 64] = sw3[tid - 64]; }
    else if (tid < 128) { ssb2[tid - 96] = sb2[tid - 96]; }
    __syncthreads();

    const int pl = tid >> 3;             // local pair slot 0..31
    const int t  = tid & 7;              // lane within pair group
    const float* sa1 = sp;
    const float* sa2 = sp + kN * kPStr;
    const float* su1 = sp + 2 * kN * kPStr;
    const float* su2 = sp + 3 * kN * kPStr;

    for (int ch = 0; ch < 4; ++ch) {
        const int lp = ch * 32 + pl;                 // 0..127
        const bool valid = lp < 121;
        const int p = valid ? (pb * 121 + lp) : 0;   // 484 = 4*121 exactly
        const int i = p / 22, j = p - (p / 22) * 22;

        // correlation edge weight: sigmoid(relu(a1_i + a2_j) . cw2 + cb2)
        float zc = 0.f;
        {
            const float* pa1 = sa1 + i * kPStr + t * 8;
            const float* pa2 = sa2 + j * kPStr + t * 8;
            #pragma unroll
            for (int c = 0; c < 8; ++c) {
                const float h = fmaxf(pa1[c] + pa2[c], 0.f);
                zc = fmaf(h, scw2[t * 8 + c], zc);
            }
            zc += __shfl_xor(zc, 1, 64); zc += __shfl_xor(zc, 2, 64); zc += __shfl_xor(zc, 4, 64);
        }
        const float wc = 1.f / (1.f + __expf(-(zc + cb2v)));

        // semantic branch
        const int lo = (i < j) ? i : j, hi = (i < j) ? j : i;
        const float* pu1 = su1 + lo * kPStr + t * 8;
        const float* pu2 = su2 + hi * kPStr + t * 8;
        float raw[8];
        float s1 = 0.f;
        #pragma unroll
        for (int c = 0; c < 8; ++c) { raw[c] = pu1[c] + pu2[c]; s1 += raw[c]; }
        s1 += __shfl_xor(s1, 1, 64); s1 += __shfl_xor(s1, 2, 64); s1 += __shfl_xor(s1, 4, 64);
        const float mean = s1 * (1.f / 64.f);
        float s2 = 0.f;
        #pragma unroll
        for (int c = 0; c < 8; ++c) { const float d = raw[c] - mean; s2 = fmaf(d, d, s2); }
        s2 += __shfl_xor(s2, 1, 64); s2 += __shfl_xor(s2, 2, 64); s2 += __shfl_xor(s2, 4, 64);
        const float rstd = rsqrtf(s2 * (1.f / 64.f) + 1e-5f);
        {
            float* vb = vbuf + pl * 66 + t * 8;
            #pragma unroll
            for (int c = 0; c < 8; ++c) {
                const int k = t * 8 + c;
                float v = (raw[c] - mean) * rstd;
                v = fmaf(v, slng[k], slnb[k]);
                vb[c] = fmaxf(v, 0.f);
            }
        }
        // vbuf slot pl is produced and consumed by the same 8 lanes of one wave:
        // same-wave LDS ops complete in order; a full block barrier is unnecessary.
        asm volatile("s_waitcnt lgkmcnt(0)" ::: "memory");

        // 64x32 GEMV: lane owns outputs o = t*4 .. t*4+3
        float4 acc = {0, 0, 0, 0};
        {
            const float* vb = vbuf + pl * 66;
            for (int k = 0; k < 64; ++k) {
                const float v = vb[k];
                const float4 w = *((const float4*)(sw2s + k * 32 + t * 4));
                acc.x = fmaf(v, w.x, acc.x); acc.y = fmaf(v, w.y, acc.y);
                acc.z = fmaf(v, w.z, acc.z); acc.w = fmaf(v, w.w, acc.w);
            }
        }
        float z2;
        {
            const int o0 = t * 4;
            z2  = fmaxf(acc.x + ssb2[o0 + 0], 0.f) * ssw3[o0 + 0];
            z2 += fmaxf(acc.y + ssb2[o0 + 1], 0.f) * ssw3[o0 + 1];
            z2 += fmaxf(acc.z + ssb2[o0 + 2], 0.f) * ssw3[o0 + 2];
            z2 += fmaxf(acc.w + ssb2[o0 + 3], 0.f) * ssw3[o0 + 3];
            z2 += __shfl_xor(z2, 1, 64); z2 += __shfl_xor(z2, 2, 64); z2 += __shfl_xor(z2, 4, 64);
        }

        if (valid && t == 0) {
            float gsem;
            if (i == j) {
                gsem = 1.f;
            } else {
                // accurate expf: this sigmoid feeds a hard threshold compare
                const float wsem = 1.f / (1.f + expf(-(z2 + sb3v)));
                gsem = (wsem > tt) ? wsem : 0.f;
            }
            const float gcorr = fmaf(sg[p], wc, (i == j) ? 1.f : 0.f);
            out[(size_t)b * kNP + p] = fmaf(alpha, gcorr, (1.f - alpha) * gsem);
        }
    }
}

extern "C" void kernel_launch(void* const* d_in, const int* in_sizes, int n_in,
                              void* d_out, int out_size, void* d_ws, size_t ws_size,
                              hipStream_t stream)
{
    (void)n_in; (void)out_size; (void)ws_size;
    const float* x     = (const float*)d_in[0];
    const float* cw1   = (const float*)d_in[1];
    const float* cb1   = (const float*)d_in[2];
    const float* cw2   = (const float*)d_in[3];
    const float* cb2   = (const float*)d_in[4];
    const float* emb   = (const float*)d_in[5];
    const float* sw1   = (const float*)d_in[6];
    const float* sb1   = (const float*)d_in[7];
    const float* ln_g  = (const float*)d_in[8];
    const float* ln_b  = (const float*)d_in[9];
    const float* sw2   = (const float*)d_in[10];
    const float* sb2   = (const float*)d_in[11];
    const float* sw3   = (const float*)d_in[12];
    const float* sb3   = (const float*)d_in[13];
    const float* thr   = (const float*)d_in[14];
    const float* alpha = (const float*)d_in[15];
    float* out = (float*)d_out;
    float* ws  = (float*)d_ws;

    const int B = in_sizes[0] / (kN * kF);
    const int M = kN * B;
    const int Mtiles = (M + 31) / 32;
    const int nGemm = Mtiles * 4;

    float* C = ws;                           // M x 256
    float* g = ws + (size_t)M * 256;         // B x 484

    hipLaunchKernelGGL(hgc_k1, dim3(nGemm + B), dim3(256), 0, stream,
                       x, cw1, cb1, emb, sw1, sb1, C, g, M, Mtiles, nGemm);
    hipLaunchKernelGGL(hgc_k2, dim3(4 * B), dim3(256), 0, stream,
                       C, g, cw2, cb2, sw2, sb2, sw3, sb3, ln_g, ln_b, thr, alpha, out);
}

// Round 3
// 123.076 us; speedup vs baseline: 1.0547x; 1.0036x over previous
//
#include <hip/hip_runtime.h>
#include <math.h>

namespace {
constexpr int kN = 22;
constexpr int kF = 448;
constexpr int kNP = kN * kN;          // 484
// kernel1 shared pool (floats): corr role needs 22*452 + 44 = 9988 (39.95 KB)
constexpr int kXStr = 452;            // 452%4==0 (16B rows), 452%32==4 (bank spread)
constexpr int kSm1 = kN * kXStr + 2 * kN;   // 9988
// GEMM role overlays: As [64][36] = 2304, Bs [64][68] = 4352  (6656 total)
constexpr int kAStr = 36;
constexpr int kBStr = 68;
// kernel2
constexpr int kPStr = 68;
constexpr int kVStr = 68;             // vbuf row stride: 68%4==0 (16B-aligned float4 rows),
                                      // 68%32==4 so the 8 pair-groups land on distinct banks
}

// =================== kernel 1: projections GEMM + corr ======================
// blocks [0, nGemm): 32x64 SGEMM tiles of C = A(M,448) @ W(448,256)
//   col tiles: 0:a1(cw1[0:448],+cb1) 1:a2(cw1[448:896]) 2:u1(sw1[128:576],+emb@sw1[0:64],+sb1)
//              3:u2(sw1[576:1024],+emb@sw1[64:128])
// blocks [nGemm, nGemm+B): per-b corr stats + |corr| unique pairs (i<=j), mirrored write
__global__ __launch_bounds__(256) void hgc_k1(
    const float* __restrict__ x,
    const float* __restrict__ cw1, const float* __restrict__ cb1,
    const float* __restrict__ emb,
    const float* __restrict__ sw1, const float* __restrict__ sb1,
    float* __restrict__ C, float* __restrict__ g,
    int M, int Mtiles, int nGemm)
{
    __shared__ __align__(16) float sm[kSm1];
    const int tid = threadIdx.x;

    if ((int)blockIdx.x < nGemm) {
        // ---------------- GEMM role ----------------
        float* As = sm;                 // [64][kAStr] transposed: As[k][m]
        float* Bs = sm + 64 * kAStr;    // [64][kBStr]: Bs[k][n]
        const int bm = blockIdx.x % Mtiles;
        const int bn = blockIdx.x / Mtiles;        // 0..3
        const int m0 = bm * 32;

        const float* Wsrc =
            (bn == 0) ? cw1 :
            (bn == 1) ? cw1 + 448 * 64 :
            (bn == 2) ? sw1 + 128 * 64 :
                        sw1 + 576 * 64;

        const int tm = tid & 15;        // m-group: rows tm*2, tm*2+1
        const int tn = tid >> 4;        // n-group: cols tn*4 .. +3
        float acc[2][4];
        #pragma unroll
        for (int i = 0; i < 2; ++i)
            #pragma unroll
            for (int j = 0; j < 4; ++j) acc[i][j] = 0.f;

        for (int k0 = 0; k0 < kF; k0 += 64) {
            // stage A (32 rows x 64 k), transposed
            #pragma unroll
            for (int pass = 0; pass < 2; ++pass) {
                const int idx = tid + pass * 256;       // 512 float4
                const int row = idx >> 4, kq = idx & 15;
                const int m = m0 + row;
                float4 v = {0, 0, 0, 0};
                if (m < M) v = *(const float4*)&x[(size_t)m * kF + k0 + kq * 4];
                As[(kq * 4 + 0) * kAStr + row] = v.x;
                As[(kq * 4 + 1) * kAStr + row] = v.y;
                As[(kq * 4 + 2) * kAStr + row] = v.z;
                As[(kq * 4 + 3) * kAStr + row] = v.w;
            }
            // stage B (64 k x 64 n)
            #pragma unroll
            for (int pass = 0; pass < 4; ++pass) {
                const int idx = tid + pass * 256;       // 1024 float4
                const int k = idx >> 4, nq = idx & 15;
                const float4 v = *(const float4*)&Wsrc[(size_t)(k0 + k) * 64 + nq * 4];
                *(float4*)&Bs[k * kBStr + nq * 4] = v;
            }
            __syncthreads();
            #pragma unroll 8
            for (int k = 0; k < 64; ++k) {
                const float2 a2 = *(const float2*)&As[k * kAStr + tm * 2];
                const float4 b4 = *(const float4*)&Bs[k * kBStr + tn * 4];
                acc[0][0] = fmaf(a2.x, b4.x, acc[0][0]);
                acc[0][1] = fmaf(a2.x, b4.y, acc[0][1]);
                acc[0][2] = fmaf(a2.x, b4.z, acc[0][2]);
                acc[0][3] = fmaf(a2.x, b4.w, acc[0][3]);
                acc[1][0] = fmaf(a2.y, b4.x, acc[1][0]);
                acc[1][1] = fmaf(a2.y, b4.y, acc[1][1]);
                acc[1][2] = fmaf(a2.y, b4.z, acc[1][2]);
                acc[1][3] = fmaf(a2.y, b4.w, acc[1][3]);
            }
            __syncthreads();
        }

        // emb epilogue for u1/u2 tiles: extra K=64 with A=emb[r(m)], B=sw1[0:64 or 64:128]
        if (bn >= 2) {
            const float* W2 = sw1 + (bn == 2 ? 0 : 64) * 64;
            #pragma unroll
            for (int pass = 0; pass < 2; ++pass) {
                const int idx = tid + pass * 256;
                const int row = idx >> 4, kq = idx & 15;
                const int r = (m0 + row) % kN;
                const float4 v = *(const float4*)&emb[(size_t)r * 64 + kq * 4];
                As[(kq * 4 + 0) * kAStr + row] = v.x;
                As[(kq * 4 + 1) * kAStr + row] = v.y;
                As[(kq * 4 + 2) * kAStr + row] = v.z;
                As[(kq * 4 + 3) * kAStr + row] = v.w;
            }
            #pragma unroll
            for (int pass = 0; pass < 4; ++pass) {
                const int idx = tid + pass * 256;
                const int k = idx >> 4, nq = idx & 15;
                const float4 v = *(const float4*)&W2[(size_t)k * 64 + nq * 4];
                *(float4*)&Bs[k * kBStr + nq * 4] = v;
            }
            __syncthreads();
            #pragma unroll 8
            for (int k = 0; k < 64; ++k) {
                const float2 a2 = *(const float2*)&As[k * kAStr + tm * 2];
                const float4 b4 = *(const float4*)&Bs[k * kBStr + tn * 4];
                acc[0][0] = fmaf(a2.x, b4.x, acc[0][0]);
                acc[0][1] = fmaf(a2.x, b4.y, acc[0][1]);
                acc[0][2] = fmaf(a2.x, b4.z, acc[0][2]);
                acc[0][3] = fmaf(a2.x, b4.w, acc[0][3]);
                acc[1][0] = fmaf(a2.y, b4.x, acc[1][0]);
                acc[1][1] = fmaf(a2.y, b4.y, acc[1][1]);
                acc[1][2] = fmaf(a2.y, b4.z, acc[1][2]);
                acc[1][3] = fmaf(a2.y, b4.w, acc[1][3]);
            }
        }

        float4 bias = {0, 0, 0, 0};
        if (bn == 0)      bias = *(const float4*)&cb1[tn * 4];
        else if (bn == 2) bias = *(const float4*)&sb1[tn * 4];
        #pragma unroll
        for (int i = 0; i < 2; ++i) {
            const int m = m0 + tm * 2 + i;
            if (m < M) {
                float4 o;
                o.x = acc[i][0] + bias.x; o.y = acc[i][1] + bias.y;
                o.z = acc[i][2] + bias.z; o.w = acc[i][3] + bias.w;
                *(float4*)&C[(size_t)m * 256 + bn * 64 + tn * 4] = o;
            }
        }
    } else {
        // ---------------- corr role: one block per b, unique pairs only ----------------
        float* smu = sm + kN * kXStr;
        float* sis = smu + kN;
        const int b = blockIdx.x - nGemm;

        const float4* xb4 = (const float4*)(x + (size_t)b * (kN * kF));
        for (int idx = tid; idx < kN * kF / 4; idx += 256) {
            const float4 v = xb4[idx];
            const int r = idx / 112;
            const int k = (idx - r * 112) * 4;
            float* d = sm + r * kXStr + k;
            d[0] = v.x; d[1] = v.y; d[2] = v.z; d[3] = v.w;
        }
        __syncthreads();

        {
            const int wid = tid >> 6, lane = tid & 63;
            for (int r = wid; r < kN; r += 4) {
                const float* row = sm + r * kXStr;
                float s = 0.f;
                #pragma unroll
                for (int c = 0; c < 7; ++c) s += row[c * 64 + lane];
                #pragma unroll
                for (int o = 32; o; o >>= 1) s += __shfl_xor(s, o, 64);
                const float mean = s * (1.f / 448.f);
                float ss = 0.f;
                #pragma unroll
                for (int c = 0; c < 7; ++c) { const float d = row[c * 64 + lane] - mean; ss = fmaf(d, d, ss); }
                #pragma unroll
                for (int o = 32; o; o >>= 1) ss += __shfl_xor(ss, o, 64);
                if (lane == 0) {
                    smu[r] = mean;
                    sis[r] = 1.f / (sqrtf(ss * (1.f / 447.f)) + 1e-8f);   // ddof=1
                }
            }
        }
        __syncthreads();

        // 253 unique pairs (i<=j); |corr| is symmetric, mirror the write.
        if (tid < 253) {
            int i = 0, rem = tid;
            while (rem >= kN - i) { rem -= kN - i; ++i; }
            const int j = i + rem;
            const float4* ri = (const float4*)(sm + i * kXStr);
            const float4* rj = (const float4*)(sm + j * kXStr);
            // 4 independent accumulators: break the 448-deep FMA dependency chain
            float d0 = 0.f, d1 = 0.f, d2 = 0.f, d3 = 0.f;
            for (int q = 0; q < 112; ++q) {
                const float4 a = ri[q], bq = rj[q];
                d0 = fmaf(a.x, bq.x, d0); d1 = fmaf(a.y, bq.y, d1);
                d2 = fmaf(a.z, bq.z, d2); d3 = fmaf(a.w, bq.w, d3);
            }
            const float dot = (d0 + d1) + (d2 + d3);
            const float c = (dot - 448.f * smu[i] * smu[j]) * sis[i] * sis[j] * (1.f / 448.f);
            const float av = fabsf(c);
            g[(size_t)b * kNP + i * 22 + j] = av;
            if (i != j) g[(size_t)b * kNP + j * 22 + i] = av;
        }
    }
}

// =================== kernel 2: 4 blocks/b, 121 pairs each ===================
// 512 blocks = 2 blocks/CU = 2 waves/SIMD: the second wave hides shfl/LDS latency.
// (2 blocks/b = 1 wave/SIMD regressed +4.6us in round 1 — latency fully exposed.)
__global__ __launch_bounds__(256) void hgc_k2(
    const float* __restrict__ C, const float* __restrict__ g,
    const float* __restrict__ cw2, const float* __restrict__ cb2,
    const float* __restrict__ sw2, const float* __restrict__ sb2,
    const float* __restrict__ sw3, const float* __restrict__ sb3,
    const float* __restrict__ ln_g, const float* __restrict__ ln_b,
    const float* __restrict__ thr, const float* __restrict__ alpha_p,
    float* __restrict__ out)
{
    __shared__ __align__(16) float sp[4 * kN * kPStr];   // a1|a2|u1|u2, padded rows
    __shared__ __align__(16) float sw2s[2048];
    __shared__ float scw2[64], slng[64], slnb[64], ssw3[32], ssb2[32];
    __shared__ __align__(16) float vbuf[32 * kVStr];

    const int tid = threadIdx.x;
    const int b   = blockIdx.x >> 2;
    const int pb  = blockIdx.x & 3;

    // hoist tiny scalar params once per thread
    const float cb2v  = cb2[0];
    const float sb3v  = sb3[0];
    const float tt    = 1.f / (1.f + expf(-thr[0]));      // accurate: feeds hard compare
    const float alpha = 1.f / (1.f + __expf(-alpha_p[0]));

    // stage the four 22x64 projection arrays from C rows (b*22+r), col block a*64
    #pragma unroll
    for (int a = 0; a < 4; ++a) {
        float* dst = sp + a * kN * kPStr;
        for (int idx = tid; idx < 352; idx += 256) {
            const int r = idx >> 4, kq = idx & 15;
            const float4 v = *(const float4*)&C[((size_t)(b * 22 + r)) * 256 + a * 64 + kq * 4];
            *(float4*)&dst[r * kPStr + kq * 4] = v;
        }
    }
    {
        const float4* s4 = (const float4*)sw2;
        for (int idx = tid; idx < 512; idx += 256)
            *((float4*)(sw2s + idx * 4)) = s4[idx];
    }
    if (tid < 64)       { scw2[tid] = cw2[tid]; slng[tid] = ln_g[tid]; slnb[tid] = ln_b[tid]; }
    else if (tid < 96)  { ssw3[tid - 64] = sw3[tid - 64]; }
    else if (tid < 128) { ssb2[tid - 96] = sb2[tid - 96]; }
    __syncthreads();

    const int pl = tid >> 3;             // local pair slot 0..31
    const int t  = tid & 7;              // lane within pair group
    const float* sa1 = sp;
    const float* sa2 = sp + kN * kPStr;
    const float* su1 = sp + 2 * kN * kPStr;
    const float* su2 = sp + 3 * kN * kPStr;

    for (int ch = 0; ch < 4; ++ch) {
        const int lp = ch * 32 + pl;                 // 0..127
        const bool valid = lp < 121;
        const int p = valid ? (pb * 121 + lp) : 0;   // 484 = 4*121 exactly
        const int i = p / 22, j = p - (p / 22) * 22;

        // g[p] used only at the very end of the chunk: issue the load now so
        // vmcnt covers it with ~the entire chunk of compute (one 4B load per lane,
        // 8-way shared within the pair group; L2-hot, no LDS staging needed).
        const float gv = valid ? g[(size_t)b * kNP + p] : 0.f;

        // correlation edge weight: sigmoid(relu(a1_i + a2_j) . cw2 + cb2)
        float zc = 0.f;
        {
            const float* pa1 = sa1 + i * kPStr + t * 8;
            const float* pa2 = sa2 + j * kPStr + t * 8;
            #pragma unroll
            for (int c = 0; c < 8; ++c) {
                const float h = fmaxf(pa1[c] + pa2[c], 0.f);
                zc = fmaf(h, scw2[t * 8 + c], zc);
            }
            zc += __shfl_xor(zc, 1, 64); zc += __shfl_xor(zc, 2, 64); zc += __shfl_xor(zc, 4, 64);
        }
        const float wc = 1.f / (1.f + __expf(-(zc + cb2v)));

        // semantic branch
        const int lo = (i < j) ? i : j, hi = (i < j) ? j : i;
        const float* pu1 = su1 + lo * kPStr + t * 8;
        const float* pu2 = su2 + hi * kPStr + t * 8;
        float raw[8];
        float s1 = 0.f;
        #pragma unroll
        for (int c = 0; c < 8; ++c) { raw[c] = pu1[c] + pu2[c]; s1 += raw[c]; }
        s1 += __shfl_xor(s1, 1, 64); s1 += __shfl_xor(s1, 2, 64); s1 += __shfl_xor(s1, 4, 64);
        const float mean = s1 * (1.f / 64.f);
        float s2 = 0.f;
        #pragma unroll
        for (int c = 0; c < 8; ++c) { const float d = raw[c] - mean; s2 = fmaf(d, d, s2); }
        s2 += __shfl_xor(s2, 1, 64); s2 += __shfl_xor(s2, 2, 64); s2 += __shfl_xor(s2, 4, 64);
        const float rstd = rsqrtf(s2 * (1.f / 64.f) + 1e-5f);
        {
            float* vb = vbuf + pl * kVStr + t * 8;
            #pragma unroll
            for (int c = 0; c < 8; ++c) {
                const int k = t * 8 + c;
                float v = (raw[c] - mean) * rstd;
                v = fmaf(v, slng[k], slnb[k]);
                vb[c] = fmaxf(v, 0.f);
            }
        }
        // vbuf slot pl is produced and consumed by the same 8 lanes of one wave:
        // same-wave LDS ops complete in order; a full block barrier is unnecessary.
        asm volatile("s_waitcnt lgkmcnt(0)" ::: "memory");

        // 64x32 GEMV: lane owns outputs o = t*4 .. t*4+3
        // float4 vbuf reads (16 b128 instead of 64 b32): same FP order, fewer DS ops.
        float4 acc = {0, 0, 0, 0};
        {
            const float4* vb4 = (const float4*)(vbuf + pl * kVStr);
            const float* wbase = sw2s + t * 4;
            #pragma unroll 4
            for (int kk = 0; kk < 16; ++kk) {
                const float4 vv = vb4[kk];
                const float4 w0 = *(const float4*)(wbase + (kk * 4 + 0) * 32);
                const float4 w1 = *(const float4*)(wbase + (kk * 4 + 1) * 32);
                const float4 w2 = *(const float4*)(wbase + (kk * 4 + 2) * 32);
                const float4 w3 = *(const float4*)(wbase + (kk * 4 + 3) * 32);
                acc.x = fmaf(vv.x, w0.x, acc.x); acc.y = fmaf(vv.x, w0.y, acc.y);
                acc.z = fmaf(vv.x, w0.z, acc.z); acc.w = fmaf(vv.x, w0.w, acc.w);
                acc.x = fmaf(vv.y, w1.x, acc.x); acc.y = fmaf(vv.y, w1.y, acc.y);
                acc.z = fmaf(vv.y, w1.z, acc.z); acc.w = fmaf(vv.y, w1.w, acc.w);
                acc.x = fmaf(vv.z, w2.x, acc.x); acc.y = fmaf(vv.z, w2.y, acc.y);
                acc.z = fmaf(vv.z, w2.z, acc.z); acc.w = fmaf(vv.z, w2.w, acc.w);
                acc.x = fmaf(vv.w, w3.x, acc.x); acc.y = fmaf(vv.w, w3.y, acc.y);
                acc.z = fmaf(vv.w, w3.z, acc.z); acc.w = fmaf(vv.w, w3.w, acc.w);
            }
        }
        float z2;
        {
            const int o0 = t * 4;
            z2  = fmaxf(acc.x + ssb2[o0 + 0], 0.f) * ssw3[o0 + 0];
            z2 += fmaxf(acc.y + ssb2[o0 + 1], 0.f) * ssw3[o0 + 1];
            z2 += fmaxf(acc.z + ssb2[o0 + 2], 0.f) * ssw3[o0 + 2];
            z2 += fmaxf(acc.w + ssb2[o0 + 3], 0.f) * ssw3[o0 + 3];
            z2 += __shfl_xor(z2, 1, 64); z2 += __shfl_xor(z2, 2, 64); z2 += __shfl_xor(z2, 4, 64);
        }

        if (valid && t == 0) {
            float gsem;
            if (i == j) {
                gsem = 1.f;
            } else {
                // accurate expf: this sigmoid feeds a hard threshold compare
                const float wsem = 1.f / (1.f + expf(-(z2 + sb3v)));
                gsem = (wsem > tt) ? wsem : 0.f;
            }
            const float gcorr = fmaf(gv, wc, (i == j) ? 1.f : 0.f);
            out[(size_t)b * kNP + p] = fmaf(alpha, gcorr, (1.f - alpha) * gsem);
        }
    }
}

extern "C" void kernel_launch(void* const* d_in, const int* in_sizes, int n_in,
                              void* d_out, int out_size, void* d_ws, size_t ws_size,
                              hipStream_t stream)
{
    (void)n_in; (void)out_size; (void)ws_size;
    const float* x     = (const float*)d_in[0];
    const float* cw1   = (const float*)d_in[1];
    const float* cb1   = (const float*)d_in[2];
    const float* cw2   = (const float*)d_in[3];
    const float* cb2   = (const float*)d_in[4];
    const float* emb   = (const float*)d_in[5];
    const float* sw1   = (const float*)d_in[6];
    const float* sb1   = (const float*)d_in[7];
    const float* ln_g  = (const float*)d_in[8];
    const float* ln_b  = (const float*)d_in[9];
    const float* sw2   = (const float*)d_in[10];
    const float* sb2   = (const float*)d_in[11];
    const float* sw3   = (const float*)d_in[12];
    const float* sb3   = (const float*)d_in[13];
    const float* thr   = (const float*)d_in[14];
    const float* alpha = (const float*)d_in[15];
    float* out = (float*)d_out;
    float* ws  = (float*)d_ws;

    const int B = in_sizes[0] / (kN * kF);
    const int M = kN * B;
    const int Mtiles = (M + 31) / 32;
    const int nGemm = Mtiles * 4;

    float* C = ws;                           // M x 256
    float* g = ws + (size_t)M * 256;         // B x 484

    hipLaunchKernelGGL(hgc_k1, dim3(nGemm + B), dim3(256), 0, stream,
                       x, cw1, cb1, emb, sw1, sb1, C, g, M, Mtiles, nGemm);
    hipLaunchKernelGGL(hgc_k2, dim3(4 * B), dim3(256), 0, stream,
                       C, g, cw2, cb2, sw2, sb2, sw3, sb3, ln_g, ln_b, thr, alpha, out);
}